// Round 12
// baseline (104.107 us; speedup 1.0000x reference)
//
#include <hip/hip_runtime.h>
#include <hip/hip_bf16.h>

// Weight-only int4 GEMM (M=2048, N=4096, K=4096, G=128). Plan:
//   dequant_w : packed int4 -> bf16 Wd[N][K] in d_ws
//   cvt_a     : fp32 A -> bf16 Ab[M][K] in d_ws
//   gemm_2b   : 128x128 tile, 4 waves (2x2 of 64x64), 256 thr, BK=64,
//               mfma_f32_32x32x16_bf16, 2-deep LDS ring = 64 KiB ->
//               TWO BLOCKS PER CU (512 blocks on 256 CUs). R5's proven
//               1-barrier ping-pong schedule; cross-block overlap fills
//               the matrix pipe while the other block drains/syncs (m114).
//               No split-K, no reduce pass.
// Fallback: round-1 fused kernel if ws too small.

using bf16x8 = __attribute__((ext_vector_type(8))) short;
using f32x16 = __attribute__((ext_vector_type(16))) float;
using f32x4  = __attribute__((ext_vector_type(4))) float;

#define KK 4096
#define NN 4096
#define NT (KK / 64)

static __device__ __forceinline__ short f2bf(float f) {
    __hip_bfloat16 h = __float2bfloat16(f);
    return __builtin_bit_cast(short, h);
}

#define GLDS16(gptr, lptr) __builtin_amdgcn_global_load_lds( \
    (const __attribute__((address_space(1))) void*)(gptr),   \
    (__attribute__((address_space(3))) void*)(lptr), 16, 0, 0)

#define MFMA32 __builtin_amdgcn_mfma_f32_32x32x16_bf16
#define SBAR() __builtin_amdgcn_sched_barrier(0)

// ---------------- pre-pass 1: dequant W -> bf16 ----------------
__global__ __launch_bounds__(256) void dequant_w(
    const int* __restrict__ W, const float* __restrict__ SZ,
    short* __restrict__ Wd)
{
    const int idx = blockIdx.x * 256 + threadIdx.x;   // [0, NN*512)
    const int n   = idx >> 9;
    const int q4  = idx & 511;
    const int kh0 = q4 << 2;
    const int g   = kh0 >> 6;
    const float2 sz = *(const float2*)(SZ + ((size_t)g * NN + n) * 2);
    const float scale = sz.x;
    const float zs    = sz.y - 8.0f * sz.x;           // (q-8)*s+z = q*s+zs
    int4 p = *(const int4*)(W + (size_t)n * (KK / 2) + kh0);
    int vals[4] = {p.x, p.y, p.z, p.w};
    bf16x8 r;
    #pragma unroll
    for (int j = 0; j < 4; ++j) {
        int v = vals[j];
        r[2 * j]     = f2bf((float)((v >> 4) & 0xF) * scale + zs);
        r[2 * j + 1] = f2bf((float)(v & 0xF) * scale + zs);
    }
    *(bf16x8*)&Wd[(size_t)n * KK + (kh0 << 1)] = r;
}

// ---------------- pre-pass 2: A fp32 -> bf16 ----------------
__global__ __launch_bounds__(256) void cvt_a(
    const float* __restrict__ A, short* __restrict__ Ab)
{
    const int idx = blockIdx.x * 256 + threadIdx.x;
    const float4* s = (const float4*)(A + (size_t)idx * 8);
    float4 u = s[0], v = s[1];
    bf16x8 r;
    r[0] = f2bf(u.x); r[1] = f2bf(u.y); r[2] = f2bf(u.z); r[3] = f2bf(u.w);
    r[4] = f2bf(v.x); r[5] = f2bf(v.y); r[6] = f2bf(v.z); r[7] = f2bf(v.w);
    *(bf16x8*)&Ab[(size_t)idx * 8] = r;
}

// ---------------- main GEMM: 128x128, 2 blocks/CU ----------------
// LDS(row, chunk c) holds global(row, c ^ (row&7)); chunks are 16B.
__global__ __launch_bounds__(256, 2) void gemm_2b(
    const short* __restrict__ Ab, const short* __restrict__ Bb,
    float* __restrict__ C)
{
    __shared__ short sA[2 * 128 * 64];   // 32 KiB
    __shared__ short sB[2 * 128 * 64];   // 32 KiB

    const int tid  = threadIdx.x;
    const int lane = tid & 63;
    const int wave = tid >> 6;           // 0..3
    const int wm   = wave >> 1;          // m-offset wm*64 (0..1)
    const int wn   = wave & 1;           // n-offset wn*64 (0..1)
    const int bm   = blockIdx.y * 128;
    const int bn   = blockIdx.x * 128;

    // staging: per gload_lds the wave fills 8 rows x 8 chunks linearly;
    // global source pre-swizzled: row += lane>>3, chunk (lane&7)^(lane>>3)
    const int sl = lane >> 3;
    const int sc = (lane & 7) ^ sl;
    const short* aSt = Ab + (size_t)(bm + wave * 32 + sl) * KK + sc * 8;
    const short* bSt = Bb + (size_t)(bn + wave * 32 + sl) * KK + sc * 8;

    // 32x32x16 fragment reads: row = base + (lane&31);
    // logical chunk = slice*2 + (lane>>5); phys = logical ^ (lane&7)
    const int l31 = lane & 31;
    const int lx  = lane >> 5;
    const int l7  = lane & 7;
    const int px0 = ((0 + lx) ^ l7) * 8;   // k-slice 0
    const int px1 = ((2 + lx) ^ l7) * 8;   // k-slice 1
    const int px2 = ((4 + lx) ^ l7) * 8;   // k-slice 2
    const int px3 = ((6 + lx) ^ l7) * 8;   // k-slice 3
    const int aRd = (wm * 64 + l31) * 64;
    const int bRd = (wn * 64 + l31) * 64;

    f32x16 acc00 = {}, acc01 = {}, acc10 = {}, acc11 = {};
    bf16x8 pA00, pA01, pA10, pA11, pB00, pB01, pB10, pB11;  // slices 0,1
    bf16x8 qA00, qA01, qA10, qA11, qB00, qB01, qB10, qB11;  // slices 2,3

    // ---- prologue: stage tile 0 into buf 0 ----
    #pragma unroll
    for (int l = 0; l < 4; ++l)
        GLDS16(aSt + (size_t)l * 8 * KK, &sA[(wave * 32 + l * 8) * 64]);
    #pragma unroll
    for (int l = 0; l < 4; ++l)
        GLDS16(bSt + (size_t)l * 8 * KK, &sB[(wave * 32 + l * 8) * 64]);
    asm volatile("s_waitcnt vmcnt(0)" ::: "memory");
    __builtin_amdgcn_s_barrier();

    // p-set (slices 0,1) of tile 0
    pA00 = *(const bf16x8*)&sA[aRd + px0];
    pA01 = *(const bf16x8*)&sA[aRd + px1];
    pA10 = *(const bf16x8*)&sA[aRd + 2048 + px0];
    pA11 = *(const bf16x8*)&sA[aRd + 2048 + px1];
    pB00 = *(const bf16x8*)&sB[bRd + px0];
    pB01 = *(const bf16x8*)&sB[bRd + px1];
    pB10 = *(const bf16x8*)&sB[bRd + 2048 + px0];
    pB11 = *(const bf16x8*)&sB[bRd + 2048 + px1];
    asm volatile("s_waitcnt lgkmcnt(0)" ::: "memory");
    SBAR();

    int cur = 0;
    for (int t = 0; t < NT; ++t) {
        const short* sAc = &sA[cur * 8192];
        const short* sBc = &sB[cur * 8192];
        short* sAn = &sA[(cur ^ 1) * 8192];
        short* sBn = &sB[(cur ^ 1) * 8192];
        const bool st = (t + 1 < NT);
        const int gk = (t + 1) * 64;

        // -- staging for t+1 into buf[cur^1].
        // Safe: all reads of buf[cur^1] (tile t-1) drained at each wave's own
        // lgkmcnt(0) before tile t-1's collective barrier, which precedes this.
        if (st) {
            GLDS16(aSt + (size_t)0 * 8 * KK + gk, sAn + (wave * 32 + 0) * 64);
            GLDS16(aSt + (size_t)1 * 8 * KK + gk, sAn + (wave * 32 + 8) * 64);
            GLDS16(aSt + (size_t)2 * 8 * KK + gk, sAn + (wave * 32 + 16) * 64);
            GLDS16(aSt + (size_t)3 * 8 * KK + gk, sAn + (wave * 32 + 24) * 64);
            GLDS16(bSt + (size_t)0 * 8 * KK + gk, sBn + (wave * 32 + 0) * 64);
            GLDS16(bSt + (size_t)1 * 8 * KK + gk, sBn + (wave * 32 + 8) * 64);
            GLDS16(bSt + (size_t)2 * 8 * KK + gk, sBn + (wave * 32 + 16) * 64);
            GLDS16(bSt + (size_t)3 * 8 * KK + gk, sBn + (wave * 32 + 24) * 64);
        }

        // -- q-set reads (slices 2,3) from current buffer --
        qA00 = *(const bf16x8*)&sAc[aRd + px2];
        qA01 = *(const bf16x8*)&sAc[aRd + px3];
        qA10 = *(const bf16x8*)&sAc[aRd + 2048 + px2];
        qA11 = *(const bf16x8*)&sAc[aRd + 2048 + px3];
        qB00 = *(const bf16x8*)&sBc[bRd + px2];
        qB01 = *(const bf16x8*)&sBc[bRd + px3];
        qB10 = *(const bf16x8*)&sBc[bRd + 2048 + px2];
        qB11 = *(const bf16x8*)&sBc[bRd + 2048 + px3];
        SBAR();

        // -- MFMA on p-set (overlaps q-reads + staging) --
        __builtin_amdgcn_s_setprio(1);
        acc00 = MFMA32(pA00, pB00, acc00, 0, 0, 0);
        acc00 = MFMA32(pA01, pB01, acc00, 0, 0, 0);
        acc01 = MFMA32(pA00, pB10, acc01, 0, 0, 0);
        acc01 = MFMA32(pA01, pB11, acc01, 0, 0, 0);
        acc10 = MFMA32(pA10, pB00, acc10, 0, 0, 0);
        acc10 = MFMA32(pA11, pB01, acc10, 0, 0, 0);
        acc11 = MFMA32(pA10, pB10, acc11, 0, 0, 0);
        acc11 = MFMA32(pA11, pB11, acc11, 0, 0, 0);
        __builtin_amdgcn_s_setprio(0);

        // -- drain q-reads + this tile's staging; single barrier --
        asm volatile("s_waitcnt lgkmcnt(0)" ::: "memory");
        SBAR();
        asm volatile("s_waitcnt vmcnt(0)" ::: "memory");
        __builtin_amdgcn_s_barrier();

        // -- p-set reads for t+1 from the freshly staged buffer --
        if (st) {
            pA00 = *(const bf16x8*)&sAn[aRd + px0];
            pA01 = *(const bf16x8*)&sAn[aRd + px1];
            pA10 = *(const bf16x8*)&sAn[aRd + 2048 + px0];
            pA11 = *(const bf16x8*)&sAn[aRd + 2048 + px1];
            pB00 = *(const bf16x8*)&sBn[bRd + px0];
            pB01 = *(const bf16x8*)&sBn[bRd + px1];
            pB10 = *(const bf16x8*)&sBn[bRd + 2048 + px0];
            pB11 = *(const bf16x8*)&sBn[bRd + 2048 + px1];
        }
        SBAR();

        // -- MFMA on q-set (overlaps next p-reads) --
        __builtin_amdgcn_s_setprio(1);
        acc00 = MFMA32(qA00, qB00, acc00, 0, 0, 0);
        acc00 = MFMA32(qA01, qB01, acc00, 0, 0, 0);
        acc01 = MFMA32(qA00, qB10, acc01, 0, 0, 0);
        acc01 = MFMA32(qA01, qB11, acc01, 0, 0, 0);
        acc10 = MFMA32(qA10, qB00, acc10, 0, 0, 0);
        acc10 = MFMA32(qA11, qB01, acc10, 0, 0, 0);
        acc11 = MFMA32(qA10, qB10, acc11, 0, 0, 0);
        acc11 = MFMA32(qA11, qB11, acc11, 0, 0, 0);
        __builtin_amdgcn_s_setprio(0);

        asm volatile("s_waitcnt lgkmcnt(0)" ::: "memory");
        SBAR();

        cur ^= 1;
    }

    // ---- epilogue: 32x32 C/D layout: col = lane&31,
    //      row = (reg&3) + 8*(reg>>2) + 4*(lane>>5) ----
    {
        const int crow = lx * 4;
        float* Cp = C + (size_t)(bm + wm * 64) * NN + bn + wn * 64;
        #pragma unroll
        for (int m = 0; m < 2; ++m) {
            #pragma unroll
            for (int qr = 0; qr < 4; ++qr) {
                #pragma unroll
                for (int j = 0; j < 4; ++j) {
                    const int row = m * 32 + crow + j + 8 * qr;
                    float* dst = Cp + (size_t)row * NN + l31;
                    if (m == 0) {
                        dst[0]  = acc00[qr * 4 + j];
                        dst[32] = acc01[qr * 4 + j];
                    } else {
                        dst[0]  = acc10[qr * 4 + j];
                        dst[32] = acc11[qr * 4 + j];
                    }
                }
            }
        }
    }
}

// ---------------- fallback: round-1 fused kernel ----------------
#define LDKF 72
__global__ __launch_bounds__(256) void wq4_gemm_fused(
    const float* __restrict__ A, const int* __restrict__ W,
    const float* __restrict__ SZ, float* __restrict__ C, int M)
{
    __shared__ short sA[128 * LDKF];
    __shared__ short sB[128 * LDKF];
    const int tid = threadIdx.x, lane = tid & 63, wave = tid >> 6;
    const int wr = (wave >> 1) << 6, wc = (wave & 1) << 6;
    const int bm = blockIdx.y * 128, bn = blockIdx.x * 128;
    const int ar = tid >> 2, ac = (tid & 3) << 4;
    const int br = tid >> 1, bh = (tid & 1) << 4;
    const float* Arow0 = A + (size_t)(bm + ar) * KK + ac;
    const float* Arow1 = A + (size_t)(bm + 64 + ar) * KK + ac;
    const int*   Wrow  = W + (size_t)(bn + br) * (KK / 2) + bh;
    const float* SZrow = SZ + (size_t)(bn + br) * 2;
    f32x4 acc[4][4] = {};
    for (int k0 = 0; k0 < KK; k0 += 64) {
        {
            const float4* s0 = (const float4*)(Arow0 + k0);
            const float4* s1 = (const float4*)(Arow1 + k0);
            float4 a0 = s0[0], a1 = s0[1], a2 = s0[2], a3 = s0[3];
            float4 b0 = s1[0], b1 = s1[1], b2 = s1[2], b3 = s1[3];
            auto cvt8 = [](float4 u, float4 v) -> bf16x8 {
                bf16x8 r;
                r[0] = f2bf(u.x); r[1] = f2bf(u.y); r[2] = f2bf(u.z); r[3] = f2bf(u.w);
                r[4] = f2bf(v.x); r[5] = f2bf(v.y); r[6] = f2bf(v.z); r[7] = f2bf(v.w);
                return r;
            };
            *(bf16x8*)&sA[ar * LDKF + ac]            = cvt8(a0, a1);
            *(bf16x8*)&sA[ar * LDKF + ac + 8]        = cvt8(a2, a3);
            *(bf16x8*)&sA[(64 + ar) * LDKF + ac]     = cvt8(b0, b1);
            *(bf16x8*)&sA[(64 + ar) * LDKF + ac + 8] = cvt8(b2, b3);
        }
        {
            const int g = k0 >> 7;
            const float2 sz = *(const float2*)(SZrow + (size_t)g * NN * 2);
            const float scale = sz.x, zs = sz.y - 8.0f * sz.x;
            const int4* src = (const int4*)(Wrow + (k0 >> 1));
            #pragma unroll
            for (int i = 0; i < 4; ++i) {
                int4 p = src[i];
                int vals[4] = {p.x, p.y, p.z, p.w};
                bf16x8 r;
                #pragma unroll
                for (int j = 0; j < 4; ++j) {
                    int v = vals[j];
                    r[2 * j]     = f2bf((float)((v >> 4) & 0xF) * scale + zs);
                    r[2 * j + 1] = f2bf((float)(v & 0xF) * scale + zs);
                }
                *(bf16x8*)&sB[br * LDKF + (bh << 1) + (i << 3)] = r;
            }
        }
        __syncthreads();
        #pragma unroll
        for (int ks = 0; ks < 2; ++ks) {
            const int col = (ks << 5) + ((lane >> 4) << 3);
            bf16x8 af[4], bfr[4];
            #pragma unroll
            for (int m = 0; m < 4; ++m)
                af[m] = *(const bf16x8*)&sA[(wr + m * 16 + (lane & 15)) * LDKF + col];
            #pragma unroll
            for (int n = 0; n < 4; ++n)
                bfr[n] = *(const bf16x8*)&sB[(wc + n * 16 + (lane & 15)) * LDKF + col];
            #pragma unroll
            for (int m = 0; m < 4; ++m)
                #pragma unroll
                for (int n = 0; n < 4; ++n)
                    acc[m][n] = __builtin_amdgcn_mfma_f32_16x16x32_bf16(
                        af[m], bfr[n], acc[m][n], 0, 0, 0);
        }
        __syncthreads();
    }
    float* Cp = C + (size_t)(bm + wr) * NN + bn + wc;
    const int cr = (lane >> 4) << 2, cc = lane & 15;
    #pragma unroll
    for (int m = 0; m < 4; ++m)
        #pragma unroll
        for (int j = 0; j < 4; ++j) {
            float* dst = Cp + (size_t)(m * 16 + cr + j) * NN + cc;
            #pragma unroll
            for (int n = 0; n < 4; ++n) dst[n * 16] = acc[m][n][j];
        }
}

extern "C" void kernel_launch(void* const* d_in, const int* in_sizes, int n_in,
                              void* d_out, int out_size, void* d_ws, size_t ws_size,
                              hipStream_t stream) {
    const float* A  = (const float*)d_in[0];
    const int*   W  = (const int*)d_in[1];
    const float* SZ = (const float*)d_in[2];
    float* C = (float*)d_out;

    const int M = in_sizes[0] / KK;   // 2048

    const size_t wd_e = (size_t)NN * KK;
    const size_t ab_e = (size_t)M * KK;
    const size_t need = (wd_e + ab_e) * sizeof(short);   // 48 MB

    if (ws_size >= need && (M % 128) == 0) {
        short* Wd = (short*)d_ws;
        short* Ab = Wd + wd_e;
        dequant_w<<<NN * (KK / 8) / 256, 256, 0, stream>>>(W, SZ, Wd);
        cvt_a<<<(int)(ab_e / 8 / 256), 256, 0, stream>>>(A, Ab);
        dim3 grid(NN / 128, M / 128);
        gemm_2b<<<grid, dim3(256), 0, stream>>>(Ab, Wd, C);
    } else {
        dim3 grid(NN / 128, M / 128);
        wq4_gemm_fused<<<grid, dim3(256), 0, stream>>>(A, W, SZ, C, M);
    }
}

// Round 13
// 93.735 us; speedup vs baseline: 1.1107x; 1.1107x over previous
//
#include <hip/hip_runtime.h>
#include <hip/hip_bf16.h>

// Weight-only int4 GEMM (M=2048, N=4096, K=4096, G=128). Plan:
//   dequant_w : packed int4 -> bf16 Wd[N][K] in d_ws
//   cvt_a     : fp32 A -> bf16 Ab[M][K] in d_ws
//   gemm_nf   : R5 pipelined GEMM (BM=256 x BN=128, BK=64, 8 waves of 64x64,
//               mfma_f32_32x32x16_bf16, 3-deep LDS ring, ONE barrier +
//               counted vmcnt(3) per K-tile) WITH the redundant explicit
//               lgkmcnt(0) drains removed: RAW is handled by the compiler's
//               counted lgkmcnt before each dependent MFMA; WAR spans a full
//               tile + barrier. Only vmcnt(3) + barrier remain per tile.
// Fallback: round-1 fused kernel if ws too small.

using bf16x8 = __attribute__((ext_vector_type(8))) short;
using f32x16 = __attribute__((ext_vector_type(16))) float;
using f32x4  = __attribute__((ext_vector_type(4))) float;

#define KK 4096
#define NN 4096
#define NT (KK / 64)

static __device__ __forceinline__ short f2bf(float f) {
    __hip_bfloat16 h = __float2bfloat16(f);
    return __builtin_bit_cast(short, h);
}

#define GLDS16(gptr, lptr) __builtin_amdgcn_global_load_lds( \
    (const __attribute__((address_space(1))) void*)(gptr),   \
    (__attribute__((address_space(3))) void*)(lptr), 16, 0, 0)

#define MFMA32 __builtin_amdgcn_mfma_f32_32x32x16_bf16
#define SBAR() __builtin_amdgcn_sched_barrier(0)

// ---------------- pre-pass 1: dequant W -> bf16 ----------------
__global__ __launch_bounds__(256) void dequant_w(
    const int* __restrict__ W, const float* __restrict__ SZ,
    short* __restrict__ Wd)
{
    const int idx = blockIdx.x * 256 + threadIdx.x;   // [0, NN*512)
    const int n   = idx >> 9;
    const int q4  = idx & 511;
    const int kh0 = q4 << 2;
    const int g   = kh0 >> 6;
    const float2 sz = *(const float2*)(SZ + ((size_t)g * NN + n) * 2);
    const float scale = sz.x;
    const float zs    = sz.y - 8.0f * sz.x;           // (q-8)*s+z = q*s+zs
    int4 p = *(const int4*)(W + (size_t)n * (KK / 2) + kh0);
    int vals[4] = {p.x, p.y, p.z, p.w};
    bf16x8 r;
    #pragma unroll
    for (int j = 0; j < 4; ++j) {
        int v = vals[j];
        r[2 * j]     = f2bf((float)((v >> 4) & 0xF) * scale + zs);
        r[2 * j + 1] = f2bf((float)(v & 0xF) * scale + zs);
    }
    *(bf16x8*)&Wd[(size_t)n * KK + (kh0 << 1)] = r;
}

// ---------------- pre-pass 2: A fp32 -> bf16 ----------------
__global__ __launch_bounds__(256) void cvt_a(
    const float* __restrict__ A, short* __restrict__ Ab)
{
    const int idx = blockIdx.x * 256 + threadIdx.x;
    const float4* s = (const float4*)(A + (size_t)idx * 8);
    float4 u = s[0], v = s[1];
    bf16x8 r;
    r[0] = f2bf(u.x); r[1] = f2bf(u.y); r[2] = f2bf(u.z); r[3] = f2bf(u.w);
    r[4] = f2bf(v.x); r[5] = f2bf(v.y); r[6] = f2bf(v.z); r[7] = f2bf(v.w);
    *(bf16x8*)&Ab[(size_t)idx * 8] = r;
}

// ---------------- main pipelined GEMM (1 barrier / K-tile, no fences) ----
// LDS(row, chunk c) holds global(row, c ^ (row&7)); chunks are 16B.
__global__ __launch_bounds__(512, 2) void gemm_nf(
    const short* __restrict__ Ab, const short* __restrict__ Bb,
    float* __restrict__ C)
{
    __shared__ short sA[3 * 256 * 64];   // 96 KiB
    __shared__ short sB[3 * 128 * 64];   // 48 KiB

    const int tid  = threadIdx.x;
    const int lane = tid & 63;
    const int wave = tid >> 6;           // 0..7
    const int wm   = wave >> 1;          // m-offset wm*64 (0..3)
    const int wn   = wave & 1;           // n-offset wn*64
    const int bm   = blockIdx.y * 256;
    const int bn   = blockIdx.x * 128;

    // staging: per gload_lds the wave fills 8 rows x 8 chunks linearly;
    // global source pre-swizzled: row += lane>>3, chunk (lane&7)^(lane>>3)
    const int sl = lane >> 3;
    const int sc = (lane & 7) ^ sl;
    const short* aSt = Ab + (size_t)(bm + wave * 32 + sl) * KK + sc * 8;
    const short* bSt = Bb + (size_t)(bn + wave * 16 + sl) * KK + sc * 8;

    // 32x32x16 fragment reads: row = base + (lane&31);
    // logical chunk = slice*2 + (lane>>5); phys = logical ^ (lane&7)
    const int l31 = lane & 31;
    const int lx  = lane >> 5;
    const int l7  = lane & 7;
    const int px0 = ((0 + lx) ^ l7) * 8;   // k-slice 0
    const int px1 = ((2 + lx) ^ l7) * 8;   // k-slice 1
    const int px2 = ((4 + lx) ^ l7) * 8;   // k-slice 2
    const int px3 = ((6 + lx) ^ l7) * 8;   // k-slice 3
    const int aRd = (wm * 64 + l31) * 64;
    const int bRd = (wn * 64 + l31) * 64;

    f32x16 acc00 = {}, acc01 = {}, acc10 = {}, acc11 = {};
    bf16x8 pA00, pA01, pA10, pA11, pB00, pB01, pB10, pB11;  // phase-0 frags
    bf16x8 qA00, qA01, qA10, qA11, qB00, qB01, qB10, qB11;  // phase-1 frags

    // ---- prologue: stage K-tiles 0 and 1 ----
    #pragma unroll
    for (int l = 0; l < 4; ++l)
        GLDS16(aSt + (size_t)l * 8 * KK,      &sA[(wave * 32 + l * 8) * 64]);
    #pragma unroll
    for (int l = 0; l < 2; ++l)
        GLDS16(bSt + (size_t)l * 8 * KK,      &sB[(wave * 16 + l * 8) * 64]);
    #pragma unroll
    for (int l = 0; l < 4; ++l)
        GLDS16(aSt + (size_t)l * 8 * KK + 64, &sA[16384 + (wave * 32 + l * 8) * 64]);
    #pragma unroll
    for (int l = 0; l < 2; ++l)
        GLDS16(bSt + (size_t)l * 8 * KK + 64, &sB[8192 + (wave * 16 + l * 8) * 64]);
    asm volatile("s_waitcnt vmcnt(6)" ::: "memory");   // tile 0 landed
    __builtin_amdgcn_s_barrier();

    // p-set (slices 0,1) of tile 0; compiler inserts the counted lgkm waits
    pA00 = *(const bf16x8*)&sA[aRd + px0];
    pA01 = *(const bf16x8*)&sA[aRd + px1];
    pA10 = *(const bf16x8*)&sA[aRd + 2048 + px0];
    pA11 = *(const bf16x8*)&sA[aRd + 2048 + px1];
    pB00 = *(const bf16x8*)&sB[bRd + px0];
    pB01 = *(const bf16x8*)&sB[bRd + px1];
    pB10 = *(const bf16x8*)&sB[bRd + 2048 + px0];
    pB11 = *(const bf16x8*)&sB[bRd + 2048 + px1];
    SBAR();

    int cur = 0;
    for (int t = 0; t < NT; ++t) {
        const int nxt1 = (cur == 2) ? 0 : cur + 1;     // (t+1)%3
        const int nxt2 = (nxt1 == 2) ? 0 : nxt1 + 1;   // (t+2)%3
        const short* sAc = &sA[cur * 16384];
        const short* sBc = &sB[cur * 8192];
        const short* sA1 = &sA[nxt1 * 16384];
        const short* sB1 = &sB[nxt1 * 8192];
        short* sAn = &sA[nxt2 * 16384];
        short* sBn = &sB[nxt2 * 8192];
        const bool st = (t + 2 < NT);
        const int gk = (t + 2) * 64;

        // -- issue q-set frag reads (slices 2,3) + first half staging --
        // WAR note: buf[cur] is next overwritten by staging issued in tile
        // t+1's post-region (for t+3) -> a full tile + barrier away; the
        // compiler's dependency wait before MM8(q) drains these reads long
        // before that. No explicit lgkm fence needed.
        qA00 = *(const bf16x8*)&sAc[aRd + px2];
        qA01 = *(const bf16x8*)&sAc[aRd + px3];
        qA10 = *(const bf16x8*)&sAc[aRd + 2048 + px2];
        qA11 = *(const bf16x8*)&sAc[aRd + 2048 + px3];
        qB00 = *(const bf16x8*)&sBc[bRd + px2];
        qB01 = *(const bf16x8*)&sBc[bRd + px3];
        qB10 = *(const bf16x8*)&sBc[bRd + 2048 + px2];
        qB11 = *(const bf16x8*)&sBc[bRd + 2048 + px3];
        if (st) {
            GLDS16(aSt + (size_t)0 * 8 * KK + gk, sAn + (wave * 32 + 0) * 64);
            GLDS16(aSt + (size_t)1 * 8 * KK + gk, sAn + (wave * 32 + 8) * 64);
            GLDS16(bSt + (size_t)0 * 8 * KK + gk, sBn + (wave * 16 + 0) * 64);
        }
        SBAR();

        // -- MFMA on p-set (overlaps the reads above; starts as soon as the
        //    p-frags' own counted lgkm wait clears, q-reads stay in flight) --
        __builtin_amdgcn_s_setprio(1);
        acc00 = MFMA32(pA00, pB00, acc00, 0, 0, 0);
        acc00 = MFMA32(pA01, pB01, acc00, 0, 0, 0);
        acc01 = MFMA32(pA00, pB10, acc01, 0, 0, 0);
        acc01 = MFMA32(pA01, pB11, acc01, 0, 0, 0);
        acc10 = MFMA32(pA10, pB00, acc10, 0, 0, 0);
        acc10 = MFMA32(pA11, pB01, acc10, 0, 0, 0);
        acc11 = MFMA32(pA10, pB10, acc11, 0, 0, 0);
        acc11 = MFMA32(pA11, pB11, acc11, 0, 0, 0);
        __builtin_amdgcn_s_setprio(0);

        // -- counted vmem wait (buf[t+1] fully landed) + single barrier --
        if (t < NT - 2) {
            asm volatile("s_waitcnt vmcnt(3)" ::: "memory");
        } else {
            asm volatile("s_waitcnt vmcnt(0)" ::: "memory");
        }
        __builtin_amdgcn_s_barrier();

        // -- issue next-tile p-set frag reads + second half staging --
        if (t + 1 < NT) {
            pA00 = *(const bf16x8*)&sA1[aRd + px0];
            pA01 = *(const bf16x8*)&sA1[aRd + px1];
            pA10 = *(const bf16x8*)&sA1[aRd + 2048 + px0];
            pA11 = *(const bf16x8*)&sA1[aRd + 2048 + px1];
            pB00 = *(const bf16x8*)&sB1[bRd + px0];
            pB01 = *(const bf16x8*)&sB1[bRd + px1];
            pB10 = *(const bf16x8*)&sB1[bRd + 2048 + px0];
            pB11 = *(const bf16x8*)&sB1[bRd + 2048 + px1];
        }
        if (st) {
            GLDS16(aSt + (size_t)2 * 8 * KK + gk, sAn + (wave * 32 + 16) * 64);
            GLDS16(aSt + (size_t)3 * 8 * KK + gk, sAn + (wave * 32 + 24) * 64);
            GLDS16(bSt + (size_t)1 * 8 * KK + gk, sBn + (wave * 16 + 8) * 64);
        }
        SBAR();

        // -- MFMA on q-set (overlaps the p-reads above) --
        __builtin_amdgcn_s_setprio(1);
        acc00 = MFMA32(qA00, qB00, acc00, 0, 0, 0);
        acc00 = MFMA32(qA01, qB01, acc00, 0, 0, 0);
        acc01 = MFMA32(qA00, qB10, acc01, 0, 0, 0);
        acc01 = MFMA32(qA01, qB11, acc01, 0, 0, 0);
        acc10 = MFMA32(qA10, qB00, acc10, 0, 0, 0);
        acc10 = MFMA32(qA11, qB01, acc10, 0, 0, 0);
        acc11 = MFMA32(qA10, qB10, acc11, 0, 0, 0);
        acc11 = MFMA32(qA11, qB11, acc11, 0, 0, 0);
        __builtin_amdgcn_s_setprio(0);

        cur = nxt1;
    }

    // ---- epilogue: 32x32 C/D layout: col = lane&31,
    //      row = (reg&3) + 8*(reg>>2) + 4*(lane>>5) ----
    {
        const int crow = lx * 4;
        float* Cp = C + (size_t)(bm + wm * 64) * NN + bn + wn * 64;
        #pragma unroll
        for (int m = 0; m < 2; ++m) {
            #pragma unroll
            for (int qr = 0; qr < 4; ++qr) {
                #pragma unroll
                for (int j = 0; j < 4; ++j) {
                    const int row = m * 32 + crow + j + 8 * qr;
                    float* dst = Cp + (size_t)row * NN + l31;
                    if (m == 0) {
                        dst[0]  = acc00[qr * 4 + j];
                        dst[32] = acc01[qr * 4 + j];
                    } else {
                        dst[0]  = acc10[qr * 4 + j];
                        dst[32] = acc11[qr * 4 + j];
                    }
                }
            }
        }
    }
}

// ---------------- fallback: round-1 fused kernel ----------------
#define LDKF 72
__global__ __launch_bounds__(256) void wq4_gemm_fused(
    const float* __restrict__ A, const int* __restrict__ W,
    const float* __restrict__ SZ, float* __restrict__ C, int M)
{
    __shared__ short sA[128 * LDKF];
    __shared__ short sB[128 * LDKF];
    const int tid = threadIdx.x, lane = tid & 63, wave = tid >> 6;
    const int wr = (wave >> 1) << 6, wc = (wave & 1) << 6;
    const int bm = blockIdx.y * 128, bn = blockIdx.x * 128;
    const int ar = tid >> 2, ac = (tid & 3) << 4;
    const int br = tid >> 1, bh = (tid & 1) << 4;
    const float* Arow0 = A + (size_t)(bm + ar) * KK + ac;
    const float* Arow1 = A + (size_t)(bm + 64 + ar) * KK + ac;
    const int*   Wrow  = W + (size_t)(bn + br) * (KK / 2) + bh;
    const float* SZrow = SZ + (size_t)(bn + br) * 2;
    f32x4 acc[4][4] = {};
    for (int k0 = 0; k0 < KK; k0 += 64) {
        {
            const float4* s0 = (const float4*)(Arow0 + k0);
            const float4* s1 = (const float4*)(Arow1 + k0);
            float4 a0 = s0[0], a1 = s0[1], a2 = s0[2], a3 = s0[3];
            float4 b0 = s1[0], b1 = s1[1], b2 = s1[2], b3 = s1[3];
            auto cvt8 = [](float4 u, float4 v) -> bf16x8 {
                bf16x8 r;
                r[0] = f2bf(u.x); r[1] = f2bf(u.y); r[2] = f2bf(u.z); r[3] = f2bf(u.w);
                r[4] = f2bf(v.x); r[5] = f2bf(v.y); r[6] = f2bf(v.z); r[7] = f2bf(v.w);
                return r;
            };
            *(bf16x8*)&sA[ar * LDKF + ac]            = cvt8(a0, a1);
            *(bf16x8*)&sA[ar * LDKF + ac + 8]        = cvt8(a2, a3);
            *(bf16x8*)&sA[(64 + ar) * LDKF + ac]     = cvt8(b0, b1);
            *(bf16x8*)&sA[(64 + ar) * LDKF + ac + 8] = cvt8(b2, b3);
        }
        {
            const int g = k0 >> 7;
            const float2 sz = *(const float2*)(SZrow + (size_t)g * NN * 2);
            const float scale = sz.x, zs = sz.y - 8.0f * sz.x;
            const int4* src = (const int4*)(Wrow + (k0 >> 1));
            #pragma unroll
            for (int i = 0; i < 4; ++i) {
                int4 p = src[i];
                int vals[4] = {p.x, p.y, p.z, p.w};
                bf16x8 r;
                #pragma unroll
                for (int j = 0; j < 4; ++j) {
                    int v = vals[j];
                    r[2 * j]     = f2bf((float)((v >> 4) & 0xF) * scale + zs);
                    r[2 * j + 1] = f2bf((float)(v & 0xF) * scale + zs);
                }
                *(bf16x8*)&sB[br * LDKF + (bh << 1) + (i << 3)] = r;
            }
        }
        __syncthreads();
        #pragma unroll
        for (int ks = 0; ks < 2; ++ks) {
            const int col = (ks << 5) + ((lane >> 4) << 3);
            bf16x8 af[4], bfr[4];
            #pragma unroll
            for (int m = 0; m < 4; ++m)
                af[m] = *(const bf16x8*)&sA[(wr + m * 16 + (lane & 15)) * LDKF + col];
            #pragma unroll
            for (int n = 0; n < 4; ++n)
                bfr[n] = *(const bf16x8*)&sB[(wc + n * 16 + (lane & 15)) * LDKF + col];
            #pragma unroll
            for (int m = 0; m < 4; ++m)
                #pragma unroll
                for (int n = 0; n < 4; ++n)
                    acc[m][n] = __builtin_amdgcn_mfma_f32_16x16x32_bf16(
                        af[m], bfr[n], acc[m][n], 0, 0, 0);
        }
        __syncthreads();
    }
    float* Cp = C + (size_t)(bm + wr) * NN + bn + wc;
    const int cr = (lane >> 4) << 2, cc = lane & 15;
    #pragma unroll
    for (int m = 0; m < 4; ++m)
        #pragma unroll
        for (int j = 0; j < 4; ++j) {
            float* dst = Cp + (size_t)(m * 16 + cr + j) * NN + cc;
            #pragma unroll
            for (int n = 0; n < 4; ++n) dst[n * 16] = acc[m][n][j];
        }
}

extern "C" void kernel_launch(void* const* d_in, const int* in_sizes, int n_in,
                              void* d_out, int out_size, void* d_ws, size_t ws_size,
                              hipStream_t stream) {
    const float* A  = (const float*)d_in[0];
    const int*   W  = (const int*)d_in[1];
    const float* SZ = (const float*)d_in[2];
    float* C = (float*)d_out;

    const int M = in_sizes[0] / KK;   // 2048

    const size_t wd_e = (size_t)NN * KK;
    const size_t ab_e = (size_t)M * KK;
    const size_t need = (wd_e + ab_e) * sizeof(short);   // 48 MB

    if (ws_size >= need && (M % 256) == 0) {
        short* Wd = (short*)d_ws;
        short* Ab = Wd + wd_e;
        dequant_w<<<NN * (KK / 8) / 256, 256, 0, stream>>>(W, SZ, Wd);
        cvt_a<<<(int)(ab_e / 8 / 256), 256, 0, stream>>>(A, Ab);
        dim3 grid(NN / 128, M / 256);
        gemm_nf<<<grid, dim3(512), 0, stream>>>(Ab, Wd, C);
    } else {
        dim3 grid(NN / 128, M / 128);
        wq4_gemm_fused<<<grid, dim3(256), 0, stream>>>(A, W, SZ, C, M);
    }
}

// Round 14
// 85.365 us; speedup vs baseline: 1.2196x; 1.0981x over previous
//
#include <hip/hip_runtime.h>
#include <hip/hip_bf16.h>

// Weight-only int4 GEMM (M=2048, N=4096, K=4096, G=128). Plan:
//   dequant_w : packed int4 -> bf16 Wd[N][K] in d_ws
//   cvt_a     : fp32 A -> bf16 Ab[M][K] in d_ws
//   gemm_16   : R13 pipelined GEMM (BM=256 x BN=128, BK=64, 8 waves of
//               64x64, 3-deep LDS ring, ONE barrier + counted vmcnt(3) per
//               K-tile, no explicit lgkm fences) with mfma_f32_16x16x32_bf16
//               and R3's ZERO-bank-conflict fragment read pattern (16 rows x
//               4 chunk-groups per ds_read_b128, chunk ^= row&7 swizzle).
//               The 32x32 frag pattern cost 512 conflict-cyc/tile (19%).
// Fallback: round-1 fused kernel if ws too small.

using bf16x8 = __attribute__((ext_vector_type(8))) short;
using f32x4  = __attribute__((ext_vector_type(4))) float;

#define KK 4096
#define NN 4096
#define NT (KK / 64)

static __device__ __forceinline__ short f2bf(float f) {
    __hip_bfloat16 h = __float2bfloat16(f);
    return __builtin_bit_cast(short, h);
}

#define GLDS16(gptr, lptr) __builtin_amdgcn_global_load_lds( \
    (const __attribute__((address_space(1))) void*)(gptr),   \
    (__attribute__((address_space(3))) void*)(lptr), 16, 0, 0)

#define MFMA16 __builtin_amdgcn_mfma_f32_16x16x32_bf16
#define SBAR() __builtin_amdgcn_sched_barrier(0)

// ---------------- pre-pass 1: dequant W -> bf16 ----------------
__global__ __launch_bounds__(256) void dequant_w(
    const int* __restrict__ W, const float* __restrict__ SZ,
    short* __restrict__ Wd)
{
    const int idx = blockIdx.x * 256 + threadIdx.x;   // [0, NN*512)
    const int n   = idx >> 9;
    const int q4  = idx & 511;
    const int kh0 = q4 << 2;
    const int g   = kh0 >> 6;
    const float2 sz = *(const float2*)(SZ + ((size_t)g * NN + n) * 2);
    const float scale = sz.x;
    const float zs    = sz.y - 8.0f * sz.x;           // (q-8)*s+z = q*s+zs
    int4 p = *(const int4*)(W + (size_t)n * (KK / 2) + kh0);
    int vals[4] = {p.x, p.y, p.z, p.w};
    bf16x8 r;
    #pragma unroll
    for (int j = 0; j < 4; ++j) {
        int v = vals[j];
        r[2 * j]     = f2bf((float)((v >> 4) & 0xF) * scale + zs);
        r[2 * j + 1] = f2bf((float)(v & 0xF) * scale + zs);
    }
    *(bf16x8*)&Wd[(size_t)n * KK + (kh0 << 1)] = r;
}

// ---------------- pre-pass 2: A fp32 -> bf16 ----------------
__global__ __launch_bounds__(256) void cvt_a(
    const float* __restrict__ A, short* __restrict__ Ab)
{
    const int idx = blockIdx.x * 256 + threadIdx.x;
    const float4* s = (const float4*)(A + (size_t)idx * 8);
    float4 u = s[0], v = s[1];
    bf16x8 r;
    r[0] = f2bf(u.x); r[1] = f2bf(u.y); r[2] = f2bf(u.z); r[3] = f2bf(u.w);
    r[4] = f2bf(v.x); r[5] = f2bf(v.y); r[6] = f2bf(v.z); r[7] = f2bf(v.w);
    *(bf16x8*)&Ab[(size_t)idx * 8] = r;
}

// ---------------- main pipelined GEMM (16x16x32, conflict-free reads) ----
// LDS(row, chunk c) holds global(row, c ^ (row&7)); chunks are 16B.
__global__ __launch_bounds__(512, 2) void gemm_16(
    const short* __restrict__ Ab, const short* __restrict__ Bb,
    float* __restrict__ C)
{
    __shared__ short sA[3 * 256 * 64];   // 96 KiB
    __shared__ short sB[3 * 128 * 64];   // 48 KiB

    const int tid  = threadIdx.x;
    const int lane = tid & 63;
    const int wave = tid >> 6;           // 0..7
    const int wm   = wave >> 1;          // m-offset wm*64 (0..3)
    const int wn   = wave & 1;           // n-offset wn*64
    const int bm   = blockIdx.y * 256;
    const int bn   = blockIdx.x * 128;

    // staging: per gload_lds the wave fills 8 rows x 8 chunks linearly;
    // global source pre-swizzled: row += lane>>3, chunk (lane&7)^(lane>>3)
    const int sl = lane >> 3;
    const int sc = (lane & 7) ^ sl;
    const short* aSt = Ab + (size_t)(bm + wave * 32 + sl) * KK + sc * 8;
    const short* bSt = Bb + (size_t)(bn + wave * 16 + sl) * KK + sc * 8;

    // 16x16x32 fragment reads (R3 pattern, zero conflicts):
    // row = base + m*16 + (lane&15); logical chunk = ks*4 + (lane>>4);
    // phys chunk = logical ^ (lane&7). Per instr: 16 rows x 4 chunk-groups.
    const int l15 = lane & 15;
    const int l7  = lane & 7;
    const int g4  = lane >> 4;                 // 0..3
    const int pc0 = ((0 + g4) ^ l7) * 8;       // k-slice 0 (chunks 0-3)
    const int pc1 = ((4 + g4) ^ l7) * 8;       // k-slice 1 (chunks 4-7)
    const int aRd = (wm * 64 + l15) * 64;
    const int bRd = (wn * 64 + l15) * 64;

    f32x4 acc[4][4] = {};
    bf16x8 pA[4], pB[4];   // k-slice 0 frags
    bf16x8 qA[4], qB[4];   // k-slice 1 frags

    // ---- prologue: stage K-tiles 0 and 1 ----
    #pragma unroll
    for (int l = 0; l < 4; ++l)
        GLDS16(aSt + (size_t)l * 8 * KK,      &sA[(wave * 32 + l * 8) * 64]);
    #pragma unroll
    for (int l = 0; l < 2; ++l)
        GLDS16(bSt + (size_t)l * 8 * KK,      &sB[(wave * 16 + l * 8) * 64]);
    #pragma unroll
    for (int l = 0; l < 4; ++l)
        GLDS16(aSt + (size_t)l * 8 * KK + 64, &sA[16384 + (wave * 32 + l * 8) * 64]);
    #pragma unroll
    for (int l = 0; l < 2; ++l)
        GLDS16(bSt + (size_t)l * 8 * KK + 64, &sB[8192 + (wave * 16 + l * 8) * 64]);
    asm volatile("s_waitcnt vmcnt(6)" ::: "memory");   // tile 0 landed
    __builtin_amdgcn_s_barrier();

    // k-slice 0 frags of tile 0 (compiler inserts counted lgkm waits)
    #pragma unroll
    for (int m = 0; m < 4; ++m)
        pA[m] = *(const bf16x8*)&sA[aRd + m * 1024 + pc0];
    #pragma unroll
    for (int n = 0; n < 4; ++n)
        pB[n] = *(const bf16x8*)&sB[bRd + n * 1024 + pc0];
    SBAR();

    int cur = 0;
    for (int t = 0; t < NT; ++t) {
        const int nxt1 = (cur == 2) ? 0 : cur + 1;     // (t+1)%3
        const int nxt2 = (nxt1 == 2) ? 0 : nxt1 + 1;   // (t+2)%3
        const short* sAc = &sA[cur * 16384];
        const short* sBc = &sB[cur * 8192];
        const short* sA1 = &sA[nxt1 * 16384];
        const short* sB1 = &sB[nxt1 * 8192];
        short* sAn = &sA[nxt2 * 16384];
        short* sBn = &sB[nxt2 * 8192];
        const bool st = (t + 2 < NT);
        const int gk = (t + 2) * 64;

        // -- issue k-slice-1 frag reads + first half staging --
        #pragma unroll
        for (int m = 0; m < 4; ++m)
            qA[m] = *(const bf16x8*)&sAc[aRd + m * 1024 + pc1];
        #pragma unroll
        for (int n = 0; n < 4; ++n)
            qB[n] = *(const bf16x8*)&sBc[bRd + n * 1024 + pc1];
        if (st) {
            GLDS16(aSt + (size_t)0 * 8 * KK + gk, sAn + (wave * 32 + 0) * 64);
            GLDS16(aSt + (size_t)1 * 8 * KK + gk, sAn + (wave * 32 + 8) * 64);
            GLDS16(bSt + (size_t)0 * 8 * KK + gk, sBn + (wave * 16 + 0) * 64);
        }
        SBAR();

        // -- 16 independent MFMAs on k-slice 0 (overlaps reads above) --
        __builtin_amdgcn_s_setprio(1);
        #pragma unroll
        for (int m = 0; m < 4; ++m)
            #pragma unroll
            for (int n = 0; n < 4; ++n)
                acc[m][n] = MFMA16(pA[m], pB[n], acc[m][n], 0, 0, 0);
        __builtin_amdgcn_s_setprio(0);

        // -- counted vmem wait (buf[t+1] fully landed) + single barrier --
        if (t < NT - 2) {
            asm volatile("s_waitcnt vmcnt(3)" ::: "memory");
        } else {
            asm volatile("s_waitcnt vmcnt(0)" ::: "memory");
        }
        __builtin_amdgcn_s_barrier();

        // -- issue next-tile k-slice-0 frag reads + second half staging --
        if (t + 1 < NT) {
            #pragma unroll
            for (int m = 0; m < 4; ++m)
                pA[m] = *(const bf16x8*)&sA1[aRd + m * 1024 + pc0];
            #pragma unroll
            for (int n = 0; n < 4; ++n)
                pB[n] = *(const bf16x8*)&sB1[bRd + n * 1024 + pc0];
        }
        if (st) {
            GLDS16(aSt + (size_t)2 * 8 * KK + gk, sAn + (wave * 32 + 16) * 64);
            GLDS16(aSt + (size_t)3 * 8 * KK + gk, sAn + (wave * 32 + 24) * 64);
            GLDS16(bSt + (size_t)1 * 8 * KK + gk, sBn + (wave * 16 + 8) * 64);
        }
        SBAR();

        // -- 16 independent MFMAs on k-slice 1 (overlaps reads above) --
        __builtin_amdgcn_s_setprio(1);
        #pragma unroll
        for (int m = 0; m < 4; ++m)
            #pragma unroll
            for (int n = 0; n < 4; ++n)
                acc[m][n] = MFMA16(qA[m], qB[n], acc[m][n], 0, 0, 0);
        __builtin_amdgcn_s_setprio(0);

        cur = nxt1;
    }

    // ---- epilogue: 16x16 C/D layout: col = lane&15,
    //      row = (lane>>4)*4 + reg (R2-verified) ----
    {
        float* Cp = C + (size_t)(bm + wm * 64) * NN + bn + wn * 64;
        const int cr = g4 << 2;
        #pragma unroll
        for (int m = 0; m < 4; ++m) {
            #pragma unroll
            for (int j = 0; j < 4; ++j) {
                float* dst = Cp + (size_t)(m * 16 + cr + j) * NN + l15;
                #pragma unroll
                for (int n = 0; n < 4; ++n)
                    dst[n * 16] = acc[m][n][j];
            }
        }
    }
}

// ---------------- fallback: round-1 fused kernel ----------------
#define LDKF 72
__global__ __launch_bounds__(256) void wq4_gemm_fused(
    const float* __restrict__ A, const int* __restrict__ W,
    const float* __restrict__ SZ, float* __restrict__ C, int M)
{
    __shared__ short sA[128 * LDKF];
    __shared__ short sB[128 * LDKF];
    const int tid = threadIdx.x, lane = tid & 63, wave = tid >> 6;
    const int wr = (wave >> 1) << 6, wc = (wave & 1) << 6;
    const int bm = blockIdx.y * 128, bn = blockIdx.x * 128;
    const int ar = tid >> 2, ac = (tid & 3) << 4;
    const int br = tid >> 1, bh = (tid & 1) << 4;
    const float* Arow0 = A + (size_t)(bm + ar) * KK + ac;
    const float* Arow1 = A + (size_t)(bm + 64 + ar) * KK + ac;
    const int*   Wrow  = W + (size_t)(bn + br) * (KK / 2) + bh;
    const float* SZrow = SZ + (size_t)(bn + br) * 2;
    f32x4 acc[4][4] = {};
    for (int k0 = 0; k0 < KK; k0 += 64) {
        {
            const float4* s0 = (const float4*)(Arow0 + k0);
            const float4* s1 = (const float4*)(Arow1 + k0);
            float4 a0 = s0[0], a1 = s0[1], a2 = s0[2], a3 = s0[3];
            float4 b0 = s1[0], b1 = s1[1], b2 = s1[2], b3 = s1[3];
            auto cvt8 = [](float4 u, float4 v) -> bf16x8 {
                bf16x8 r;
                r[0] = f2bf(u.x); r[1] = f2bf(u.y); r[2] = f2bf(u.z); r[3] = f2bf(u.w);
                r[4] = f2bf(v.x); r[5] = f2bf(v.y); r[6] = f2bf(v.z); r[7] = f2bf(v.w);
                return r;
            };
            *(bf16x8*)&sA[ar * LDKF + ac]            = cvt8(a0, a1);
            *(bf16x8*)&sA[ar * LDKF + ac + 8]        = cvt8(a2, a3);
            *(bf16x8*)&sA[(64 + ar) * LDKF + ac]     = cvt8(b0, b1);
            *(bf16x8*)&sA[(64 + ar) * LDKF + ac + 8] = cvt8(b2, b3);
        }
        {
            const int g = k0 >> 7;
            const float2 sz = *(const float2*)(SZrow + (size_t)g * NN * 2);
            const float scale = sz.x, zs = sz.y - 8.0f * sz.x;
            const int4* src = (const int4*)(Wrow + (k0 >> 1));
            #pragma unroll
            for (int i = 0; i < 4; ++i) {
                int4 p = src[i];
                int vals[4] = {p.x, p.y, p.z, p.w};
                bf16x8 r;
                #pragma unroll
                for (int j = 0; j < 4; ++j) {
                    int v = vals[j];
                    r[2 * j]     = f2bf((float)((v >> 4) & 0xF) * scale + zs);
                    r[2 * j + 1] = f2bf((float)(v & 0xF) * scale + zs);
                }
                *(bf16x8*)&sB[br * LDKF + (bh << 1) + (i << 3)] = r;
            }
        }
        __syncthreads();
        #pragma unroll
        for (int ks = 0; ks < 2; ++ks) {
            const int col = (ks << 5) + ((lane >> 4) << 3);
            bf16x8 af[4], bfr[4];
            #pragma unroll
            for (int m = 0; m < 4; ++m)
                af[m] = *(const bf16x8*)&sA[(wr + m * 16 + (lane & 15)) * LDKF + col];
            #pragma unroll
            for (int n = 0; n < 4; ++n)
                bfr[n] = *(const bf16x8*)&sB[(wc + n * 16 + (lane & 15)) * LDKF + col];
            #pragma unroll
            for (int m = 0; m < 4; ++m)
                #pragma unroll
                for (int n = 0; n < 4; ++n)
                    acc[m][n] = __builtin_amdgcn_mfma_f32_16x16x32_bf16(
                        af[m], bfr[n], acc[m][n], 0, 0, 0);
        }
        __syncthreads();
    }
    float* Cp = C + (size_t)(bm + wr) * NN + bn + wc;
    const int cr = (lane >> 4) << 2, cc = lane & 15;
    #pragma unroll
    for (int m = 0; m < 4; ++m)
        #pragma unroll
        for (int j = 0; j < 4; ++j) {
            float* dst = Cp + (size_t)(m * 16 + cr + j) * NN + cc;
            #pragma unroll
            for (int n = 0; n < 4; ++n) dst[n * 16] = acc[m][n][j];
        }
}

extern "C" void kernel_launch(void* const* d_in, const int* in_sizes, int n_in,
                              void* d_out, int out_size, void* d_ws, size_t ws_size,
                              hipStream_t stream) {
    const float* A  = (const float*)d_in[0];
    const int*   W  = (const int*)d_in[1];
    const float* SZ = (const float*)d_in[2];
    float* C = (float*)d_out;

    const int M = in_sizes[0] / KK;   // 2048

    const size_t wd_e = (size_t)NN * KK;
    const size_t ab_e = (size_t)M * KK;
    const size_t need = (wd_e + ab_e) * sizeof(short);   // 48 MB

    if (ws_size >= need && (M % 256) == 0) {
        short* Wd = (short*)d_ws;
        short* Ab = Wd + wd_e;
        dequant_w<<<NN * (KK / 8) / 256, 256, 0, stream>>>(W, SZ, Wd);
        cvt_a<<<(int)(ab_e / 8 / 256), 256, 0, stream>>>(A, Ab);
        dim3 grid(NN / 128, M / 256);
        gemm_16<<<grid, dim3(512), 0, stream>>>(Ab, Wd, C);
    } else {
        dim3 grid(NN / 128, M / 128);
        wq4_gemm_fused<<<grid, dim3(256), 0, stream>>>(A, W, SZ, C, M);
    }
}

// Round 15
// 83.875 us; speedup vs baseline: 1.2412x; 1.0178x over previous
//
#include <hip/hip_runtime.h>
#include <hip/hip_bf16.h>

// Weight-only int4 GEMM (M=2048, N=4096, K=4096, G=128). Plan:
//   prep      : ONE fused prepass launch — blocks [0,8192): packed int4 ->
//               bf16 Wd[N][K]; blocks [8192,10240): fp32 A -> bf16 Ab[M][K]
//   gemm_16   : R14 pipelined GEMM (unchanged, measured 65.2 us / 45% MfmaUtil,
//               0 bank conflicts): BM=256 x BN=128, BK=64, 8 waves of 64x64,
//               mfma_f32_16x16x32_bf16 with the zero-conflict 16-rows x
//               4-chunk-group read pattern (chunk ^= row&7), 3-deep LDS ring,
//               ONE barrier + counted vmcnt(3) per K-tile.
// Fallback: round-1 fused kernel if ws too small.

using bf16x8 = __attribute__((ext_vector_type(8))) short;
using f32x4  = __attribute__((ext_vector_type(4))) float;

#define KK 4096
#define NN 4096
#define NT (KK / 64)

static __device__ __forceinline__ short f2bf(float f) {
    __hip_bfloat16 h = __float2bfloat16(f);
    return __builtin_bit_cast(short, h);
}

#define GLDS16(gptr, lptr) __builtin_amdgcn_global_load_lds( \
    (const __attribute__((address_space(1))) void*)(gptr),   \
    (__attribute__((address_space(3))) void*)(lptr), 16, 0, 0)

#define MFMA16 __builtin_amdgcn_mfma_f32_16x16x32_bf16
#define SBAR() __builtin_amdgcn_sched_barrier(0)

// ---------------- fused pre-pass: dequant W + cvt A ----------------
// blocks [0, NW): dequant (NW = NN*KK/8/256 = 8192)
// blocks [NW, NW+MA): cvt_a (MA = M*KK/8/256)
__global__ __launch_bounds__(256) void prep(
    const int* __restrict__ W, const float* __restrict__ SZ,
    const float* __restrict__ A,
    short* __restrict__ Wd, short* __restrict__ Ab, int nw_blocks)
{
    if ((int)blockIdx.x < nw_blocks) {
        const int idx = blockIdx.x * 256 + threadIdx.x;   // [0, NN*512)
        const int n   = idx >> 9;
        const int q4  = idx & 511;
        const int kh0 = q4 << 2;
        const int g   = kh0 >> 6;
        const float2 sz = *(const float2*)(SZ + ((size_t)g * NN + n) * 2);
        const float scale = sz.x;
        const float zs    = sz.y - 8.0f * sz.x;           // (q-8)*s+z = q*s+zs
        int4 p = *(const int4*)(W + (size_t)n * (KK / 2) + kh0);
        int vals[4] = {p.x, p.y, p.z, p.w};
        bf16x8 r;
        #pragma unroll
        for (int j = 0; j < 4; ++j) {
            int v = vals[j];
            r[2 * j]     = f2bf((float)((v >> 4) & 0xF) * scale + zs);
            r[2 * j + 1] = f2bf((float)(v & 0xF) * scale + zs);
        }
        *(bf16x8*)&Wd[(size_t)n * KK + (kh0 << 1)] = r;
    } else {
        const int idx = (blockIdx.x - nw_blocks) * 256 + threadIdx.x;
        const float4* s = (const float4*)(A + (size_t)idx * 8);
        float4 u = s[0], v = s[1];
        bf16x8 r;
        r[0] = f2bf(u.x); r[1] = f2bf(u.y); r[2] = f2bf(u.z); r[3] = f2bf(u.w);
        r[4] = f2bf(v.x); r[5] = f2bf(v.y); r[6] = f2bf(v.z); r[7] = f2bf(v.w);
        *(bf16x8*)&Ab[(size_t)idx * 8] = r;
    }
}

// ---------------- main pipelined GEMM (R14, unchanged) ----------------
// LDS(row, chunk c) holds global(row, c ^ (row&7)); chunks are 16B.
__global__ __launch_bounds__(512, 2) void gemm_16(
    const short* __restrict__ Ab, const short* __restrict__ Bb,
    float* __restrict__ C)
{
    __shared__ short sA[3 * 256 * 64];   // 96 KiB
    __shared__ short sB[3 * 128 * 64];   // 48 KiB

    const int tid  = threadIdx.x;
    const int lane = tid & 63;
    const int wave = tid >> 6;           // 0..7
    const int wm   = wave >> 1;          // m-offset wm*64 (0..3)
    const int wn   = wave & 1;           // n-offset wn*64
    const int bm   = blockIdx.y * 256;
    const int bn   = blockIdx.x * 128;

    // staging: per gload_lds the wave fills 8 rows x 8 chunks linearly;
    // global source pre-swizzled: row += lane>>3, chunk (lane&7)^(lane>>3)
    const int sl = lane >> 3;
    const int sc = (lane & 7) ^ sl;
    const short* aSt = Ab + (size_t)(bm + wave * 32 + sl) * KK + sc * 8;
    const short* bSt = Bb + (size_t)(bn + wave * 16 + sl) * KK + sc * 8;

    // 16x16x32 fragment reads (zero conflicts):
    // row = base + m*16 + (lane&15); logical chunk = ks*4 + (lane>>4);
    // phys chunk = logical ^ (lane&7). Per instr: 16 rows x 4 chunk-groups.
    const int l15 = lane & 15;
    const int l7  = lane & 7;
    const int g4  = lane >> 4;                 // 0..3
    const int pc0 = ((0 + g4) ^ l7) * 8;       // k-slice 0 (chunks 0-3)
    const int pc1 = ((4 + g4) ^ l7) * 8;       // k-slice 1 (chunks 4-7)
    const int aRd = (wm * 64 + l15) * 64;
    const int bRd = (wn * 64 + l15) * 64;

    f32x4 acc[4][4] = {};
    bf16x8 pA[4], pB[4];   // k-slice 0 frags
    bf16x8 qA[4], qB[4];   // k-slice 1 frags

    // ---- prologue: stage K-tiles 0 and 1 ----
    #pragma unroll
    for (int l = 0; l < 4; ++l)
        GLDS16(aSt + (size_t)l * 8 * KK,      &sA[(wave * 32 + l * 8) * 64]);
    #pragma unroll
    for (int l = 0; l < 2; ++l)
        GLDS16(bSt + (size_t)l * 8 * KK,      &sB[(wave * 16 + l * 8) * 64]);
    #pragma unroll
    for (int l = 0; l < 4; ++l)
        GLDS16(aSt + (size_t)l * 8 * KK + 64, &sA[16384 + (wave * 32 + l * 8) * 64]);
    #pragma unroll
    for (int l = 0; l < 2; ++l)
        GLDS16(bSt + (size_t)l * 8 * KK + 64, &sB[8192 + (wave * 16 + l * 8) * 64]);
    asm volatile("s_waitcnt vmcnt(6)" ::: "memory");   // tile 0 landed
    __builtin_amdgcn_s_barrier();

    // k-slice 0 frags of tile 0 (compiler inserts counted lgkm waits)
    #pragma unroll
    for (int m = 0; m < 4; ++m)
        pA[m] = *(const bf16x8*)&sA[aRd + m * 1024 + pc0];
    #pragma unroll
    for (int n = 0; n < 4; ++n)
        pB[n] = *(const bf16x8*)&sB[bRd + n * 1024 + pc0];
    SBAR();

    int cur = 0;
    for (int t = 0; t < NT; ++t) {
        const int nxt1 = (cur == 2) ? 0 : cur + 1;     // (t+1)%3
        const int nxt2 = (nxt1 == 2) ? 0 : nxt1 + 1;   // (t+2)%3
        const short* sAc = &sA[cur * 16384];
        const short* sBc = &sB[cur * 8192];
        const short* sA1 = &sA[nxt1 * 16384];
        const short* sB1 = &sB[nxt1 * 8192];
        short* sAn = &sA[nxt2 * 16384];
        short* sBn = &sB[nxt2 * 8192];
        const bool st = (t + 2 < NT);
        const int gk = (t + 2) * 64;

        // -- issue k-slice-1 frag reads + first half staging --
        #pragma unroll
        for (int m = 0; m < 4; ++m)
            qA[m] = *(const bf16x8*)&sAc[aRd + m * 1024 + pc1];
        #pragma unroll
        for (int n = 0; n < 4; ++n)
            qB[n] = *(const bf16x8*)&sBc[bRd + n * 1024 + pc1];
        if (st) {
            GLDS16(aSt + (size_t)0 * 8 * KK + gk, sAn + (wave * 32 + 0) * 64);
            GLDS16(aSt + (size_t)1 * 8 * KK + gk, sAn + (wave * 32 + 8) * 64);
            GLDS16(bSt + (size_t)0 * 8 * KK + gk, sBn + (wave * 16 + 0) * 64);
        }
        SBAR();

        // -- 16 independent MFMAs on k-slice 0 (overlaps reads above) --
        __builtin_amdgcn_s_setprio(1);
        #pragma unroll
        for (int m = 0; m < 4; ++m)
            #pragma unroll
            for (int n = 0; n < 4; ++n)
                acc[m][n] = MFMA16(pA[m], pB[n], acc[m][n], 0, 0, 0);
        __builtin_amdgcn_s_setprio(0);

        // -- counted vmem wait (buf[t+1] fully landed) + single barrier --
        if (t < NT - 2) {
            asm volatile("s_waitcnt vmcnt(3)" ::: "memory");
        } else {
            asm volatile("s_waitcnt vmcnt(0)" ::: "memory");
        }
        __builtin_amdgcn_s_barrier();

        // -- issue next-tile k-slice-0 frag reads + second half staging --
        if (t + 1 < NT) {
            #pragma unroll
            for (int m = 0; m < 4; ++m)
                pA[m] = *(const bf16x8*)&sA1[aRd + m * 1024 + pc0];
            #pragma unroll
            for (int n = 0; n < 4; ++n)
                pB[n] = *(const bf16x8*)&sB1[bRd + n * 1024 + pc0];
        }
        if (st) {
            GLDS16(aSt + (size_t)2 * 8 * KK + gk, sAn + (wave * 32 + 16) * 64);
            GLDS16(aSt + (size_t)3 * 8 * KK + gk, sAn + (wave * 32 + 24) * 64);
            GLDS16(bSt + (size_t)1 * 8 * KK + gk, sBn + (wave * 16 + 8) * 64);
        }
        SBAR();

        // -- 16 independent MFMAs on k-slice 1 (overlaps reads above) --
        __builtin_amdgcn_s_setprio(1);
        #pragma unroll
        for (int m = 0; m < 4; ++m)
            #pragma unroll
            for (int n = 0; n < 4; ++n)
                acc[m][n] = MFMA16(qA[m], qB[n], acc[m][n], 0, 0, 0);
        __builtin_amdgcn_s_setprio(0);

        cur = nxt1;
    }

    // ---- epilogue: 16x16 C/D layout: col = lane&15, row = (lane>>4)*4+reg ----
    {
        float* Cp = C + (size_t)(bm + wm * 64) * NN + bn + wn * 64;
        const int cr = g4 << 2;
        #pragma unroll
        for (int m = 0; m < 4; ++m) {
            #pragma unroll
            for (int j = 0; j < 4; ++j) {
                float* dst = Cp + (size_t)(m * 16 + cr + j) * NN + l15;
                #pragma unroll
                for (int n = 0; n < 4; ++n)
                    dst[n * 16] = acc[m][n][j];
            }
        }
    }
}

// ---------------- fallback: round-1 fused kernel ----------------
#define LDKF 72
__global__ __launch_bounds__(256) void wq4_gemm_fused(
    const float* __restrict__ A, const int* __restrict__ W,
    const float* __restrict__ SZ, float* __restrict__ C, int M)
{
    __shared__ short sA[128 * LDKF];
    __shared__ short sB[128 * LDKF];
    const int tid = threadIdx.x, lane = tid & 63, wave = tid >> 6;
    const int wr = (wave >> 1) << 6, wc = (wave & 1) << 6;
    const int bm = blockIdx.y * 128, bn = blockIdx.x * 128;
    const int ar = tid >> 2, ac = (tid & 3) << 4;
    const int br = tid >> 1, bh = (tid & 1) << 4;
    const float* Arow0 = A + (size_t)(bm + ar) * KK + ac;
    const float* Arow1 = A + (size_t)(bm + 64 + ar) * KK + ac;
    const int*   Wrow  = W + (size_t)(bn + br) * (KK / 2) + bh;
    const float* SZrow = SZ + (size_t)(bn + br) * 2;
    f32x4 acc[4][4] = {};
    for (int k0 = 0; k0 < KK; k0 += 64) {
        {
            const float4* s0 = (const float4*)(Arow0 + k0);
            const float4* s1 = (const float4*)(Arow1 + k0);
            float4 a0 = s0[0], a1 = s0[1], a2 = s0[2], a3 = s0[3];
            float4 b0 = s1[0], b1 = s1[1], b2 = s1[2], b3 = s1[3];
            auto cvt8 = [](float4 u, float4 v) -> bf16x8 {
                bf16x8 r;
                r[0] = f2bf(u.x); r[1] = f2bf(u.y); r[2] = f2bf(u.z); r[3] = f2bf(u.w);
                r[4] = f2bf(v.x); r[5] = f2bf(v.y); r[6] = f2bf(v.z); r[7] = f2bf(v.w);
                return r;
            };
            *(bf16x8*)&sA[ar * LDKF + ac]            = cvt8(a0, a1);
            *(bf16x8*)&sA[ar * LDKF + ac + 8]        = cvt8(a2, a3);
            *(bf16x8*)&sA[(64 + ar) * LDKF + ac]     = cvt8(b0, b1);
            *(bf16x8*)&sA[(64 + ar) * LDKF + ac + 8] = cvt8(b2, b3);
        }
        {
            const int g = k0 >> 7;
            const float2 sz = *(const float2*)(SZrow + (size_t)g * NN * 2);
            const float scale = sz.x, zs = sz.y - 8.0f * sz.x;
            const int4* src = (const int4*)(Wrow + (k0 >> 1));
            #pragma unroll
            for (int i = 0; i < 4; ++i) {
                int4 p = src[i];
                int vals[4] = {p.x, p.y, p.z, p.w};
                bf16x8 r;
                #pragma unroll
                for (int j = 0; j < 4; ++j) {
                    int v = vals[j];
                    r[2 * j]     = f2bf((float)((v >> 4) & 0xF) * scale + zs);
                    r[2 * j + 1] = f2bf((float)(v & 0xF) * scale + zs);
                }
                *(bf16x8*)&sB[br * LDKF + (bh << 1) + (i << 3)] = r;
            }
        }
        __syncthreads();
        #pragma unroll
        for (int ks = 0; ks < 2; ++ks) {
            const int col = (ks << 5) + ((lane >> 4) << 3);
            bf16x8 af[4], bfr[4];
            #pragma unroll
            for (int m = 0; m < 4; ++m)
                af[m] = *(const bf16x8*)&sA[(wr + m * 16 + (lane & 15)) * LDKF + col];
            #pragma unroll
            for (int n = 0; n < 4; ++n)
                bfr[n] = *(const bf16x8*)&sB[(wc + n * 16 + (lane & 15)) * LDKF + col];
            #pragma unroll
            for (int m = 0; m < 4; ++m)
                #pragma unroll
                for (int n = 0; n < 4; ++n)
                    acc[m][n] = __builtin_amdgcn_mfma_f32_16x16x32_bf16(
                        af[m], bfr[n], acc[m][n], 0, 0, 0);
        }
        __syncthreads();
    }
    float* Cp = C + (size_t)(bm + wr) * NN + bn + wc;
    const int cr = (lane >> 4) << 2, cc = lane & 15;
    #pragma unroll
    for (int m = 0; m < 4; ++m)
        #pragma unroll
        for (int j = 0; j < 4; ++j) {
            float* dst = Cp + (size_t)(m * 16 + cr + j) * NN + cc;
            #pragma unroll
            for (int n = 0; n < 4; ++n) dst[n * 16] = acc[m][n][j];
        }
}

extern "C" void kernel_launch(void* const* d_in, const int* in_sizes, int n_in,
                              void* d_out, int out_size, void* d_ws, size_t ws_size,
                              hipStream_t stream) {
    const float* A  = (const float*)d_in[0];
    const int*   W  = (const int*)d_in[1];
    const float* SZ = (const float*)d_in[2];
    float* C = (float*)d_out;

    const int M = in_sizes[0] / KK;   // 2048

    const size_t wd_e = (size_t)NN * KK;
    const size_t ab_e = (size_t)M * KK;
    const size_t need = (wd_e + ab_e) * sizeof(short);   // 48 MB

    if (ws_size >= need && (M % 256) == 0) {
        short* Wd = (short*)d_ws;
        short* Ab = Wd + wd_e;
        const int nw_blocks = NN * (KK / 8) / 256;        // 8192
        const int ma_blocks = (int)(ab_e / 8 / 256);      // 2048
        prep<<<nw_blocks + ma_blocks, 256, 0, stream>>>(W, SZ, A, Wd, Ab, nw_blocks);
        dim3 grid(NN / 128, M / 256);
        gemm_16<<<grid, dim3(512), 0, stream>>>(Ab, Wd, C);
    } else {
        dim3 grid(NN / 128, M / 128);
        wq4_gemm_fused<<<grid, dim3(256), 0, stream>>>(A, W, SZ, C, M);
    }
}